// Round 13
// baseline (150.441 us; speedup 1.0000x reference)
//
#include <hip/hip_runtime.h>
#include <hip/hip_bf16.h>

#define DM 1024
#define NH 16
#define DK 64
#define TT 2048
#define NBATCH 4
#define BT 8192   // NBATCH*TT

typedef __attribute__((ext_vector_type(8))) short short8;
typedef __attribute__((ext_vector_type(4))) float f32x4;
typedef unsigned short u16;

#define MFMA(a,b,c) __builtin_amdgcn_mfma_f32_16x16x32_bf16((a),(b),(c),0,0,0)

// 1/sqrt(64) * log2(e): folded into Q so attn softmax can use exp2 directly
#define QSCALE 0.18033688011112684f

// raw v_exp_f32 (flush-denorm fine for softmax), skips OCML fixup code
#define EXP2(x) __builtin_amdgcn_exp2f(x)

__device__ __forceinline__ u16 f2bf(float f){
  union { float f; unsigned u; } v; v.f = f;
  return (u16)((v.u + 0x7fffu + ((v.u >> 16) & 1u)) >> 16);
}

__device__ __forceinline__ unsigned cvtpk(float lo, float hi){
  unsigned r;
  asm("v_cvt_pk_bf16_f32 %0, %1, %2" : "=v"(r) : "v"(lo), "v"(hi));
  return r;
}

// async global->LDS DMA, 16B/lane. LDS dest must be wave-uniform base (+lane*16).
__device__ __forceinline__ void gload16(const void* g, void* l){
  __builtin_amdgcn_global_load_lds((__attribute__((address_space(1))) void*)(g),
                                   (__attribute__((address_space(3))) void*)(l), 16, 0, 0);
}

// cross-lane reduce over the 4 16-lane groups (lane ^16, ^32): pure-VALU permlanes
__device__ __forceinline__ float plmax(float x){
#if __has_builtin(__builtin_amdgcn_permlane16_swap) && __has_builtin(__builtin_amdgcn_permlane32_swap)
  auto r = __builtin_amdgcn_permlane16_swap(__float_as_uint(x), __float_as_uint(x), false, false);
  x = fmaxf(__uint_as_float(r[0]), __uint_as_float(r[1]));
  auto r2 = __builtin_amdgcn_permlane32_swap(__float_as_uint(x), __float_as_uint(x), false, false);
  x = fmaxf(__uint_as_float(r2[0]), __uint_as_float(r2[1]));
#else
  x = fmaxf(x, __shfl_xor(x, 16, 64));
  x = fmaxf(x, __shfl_xor(x, 32, 64));
#endif
  return x;
}

__device__ __forceinline__ float plsum(float x){
#if __has_builtin(__builtin_amdgcn_permlane16_swap) && __has_builtin(__builtin_amdgcn_permlane32_swap)
  auto r = __builtin_amdgcn_permlane16_swap(__float_as_uint(x), __float_as_uint(x), false, false);
  x = __uint_as_float(r[0]) + __uint_as_float(r[1]);
  auto r2 = __builtin_amdgcn_permlane32_swap(__float_as_uint(x), __float_as_uint(x), false, false);
  x = __uint_as_float(r2[0]) + __uint_as_float(r2[1]);
#else
  x = x + __shfl_xor(x, 16, 64);
  x = x + __shfl_xor(x, 32, 64);
#endif
  return x;
}

// ---------------- prep: x fp32->bf16  +  W (K,N) fp32 -> wt (N,K) bf16 ----------------
// merged single launch (block-uniform branch): blocks [0,8192) convert x,
// blocks [8192, 8192+3072) transpose+convert the three weight matrices.
__global__ __launch_bounds__(256) void prep(
    const float* __restrict__ x, u16* __restrict__ xb,
    const float* __restrict__ Wq, const float* __restrict__ Wk, const float* __restrict__ Wv,
    u16* __restrict__ wtq, u16* __restrict__ wtk, u16* __restrict__ wtv){
  __shared__ float tile[32][33];
  const int id = blockIdx.x;
  if(id < 8192){
    int i = (id * 256 + threadIdx.x) * 4;
    float4 v = *(const float4*)(x + i);
    ushort4 o; o.x = f2bf(v.x); o.y = f2bf(v.y); o.z = f2bf(v.z); o.w = f2bf(v.w);
    *(ushort4*)(xb + i) = o;
  } else {
    int r3 = id - 8192;                 // 0..3071
    int z = r3 >> 10;                   // 0..2
    int rem = r3 & 1023;
    int bx = rem & 31, by = rem >> 5;
    const float* W = (z == 0) ? Wq : (z == 1) ? Wk : Wv;
    u16* wt = (z == 0) ? wtq : (z == 1) ? wtk : wtv;
    int k0 = bx * 32, n0 = by * 32;
    int tx = threadIdx.x & 31, ty = threadIdx.x >> 5;
    #pragma unroll
    for(int r = ty; r < 32; r += 8)
      tile[r][tx] = W[(size_t)(k0 + r) * DM + n0 + tx];
    __syncthreads();
    #pragma unroll
    for(int r = ty; r < 32; r += 8)
      wt[(size_t)(n0 + r) * DM + k0 + tx] = f2bf(tile[tx][r]);
  }
}

// ---------------- QKV projection GEMM: 2-phase dbuf, BK=32, 3 blocks/CU ----------------
// Occupancy lever (R12/R13): qkv was at 2 blk/CU (64KB LDS) with Occ 19.6% and no
// pipe saturated — the skill-table latency/occupancy signature. BK 64->32 halves
// LDS to 32KB, padded to 48KB via the dynamic-shared request so exactly
// floor(160/48) = 3 blk/CU = 12 waves/CU, and grid 1536 = 2 EXACT dispatch
// rounds (4 blk/CU would give 1.5 rounds -> tail, the R7 poison).
// Same verified dbuf schedule: prefetch t+1 issued after the barrier into buf^1,
// drained at the NEXT barrier. 32 K-steps of {8 ds_read_b128, 16 MFMA}.
// Swizzle for 64B rows: slot = hi ^ ((row>>2)&3) -> max 2-way bank aliasing
// (free, m136); staging source inverse-permuted to match (rule 21).
// NOTE (R12 compile lesson): dynamic-LDS pointers must be computed as scalar
// expressions (smem + cur*8192) — a local pointer ARRAY initialized from the
// extern-shared base trips "unsupported expression in static initializer".
// XCD-locality 1-D grid; V^T store KEY-PERMUTED (attn PV needs kappa order).
__global__ __launch_bounds__(256) void qkv_gemm(
    const u16* __restrict__ xb,
    const u16* __restrict__ wtq, const u16* __restrict__ wtk, const u16* __restrict__ wtv,
    const float* __restrict__ bq, const float* __restrict__ bk, const float* __restrict__ bv,
    u16* __restrict__ qws, u16* __restrict__ kws, u16* __restrict__ vtws){
  extern __shared__ char smem[];      // 49152 requested; 32768 used (pad -> 3 blk/CU)
  // layout: A buf0 @0, A buf1 @8192, B buf0 @16384, B buf1 @24576

  const int id = blockIdx.x;              // 0..1535
  const int idx = id >> 3;                // 0..191 within XCD
  const int mt = (id & 7) * 8 + (idx & 7);// M-tile 0..63
  const int y  = idx >> 3;                // weight panel 0..23
  const int m0 = mt * 128;
  const int ng = y * 128;
  const int mat = ng >> 10;
  const int n0 = ng & 1023;
  const u16* wt = (mat == 0) ? wtq : (mat == 1) ? wtk : wtv;
  const float* bias = (mat == 0) ? bq : (mat == 1) ? bk : bv;
  const int tid = threadIdx.x;
  const int lane = tid & 63;
  const int w = tid >> 6;
  const int ln16 = lane & 15, hi = lane >> 4;
  const int wm = (w >> 1) * 64, wn = (w & 1) * 64;

  // staging geometry (per 128x32 panel): 512 chunks of 16B, 2 passes x 256 thr
  const int srow0 = (tid) >> 2;                 // pass 0 row
  const int schs0 = (tid & 3) ^ ((srow0 >> 2) & 3);
  const int srow1 = (256 + tid) >> 2;           // pass 1 row
  const int schs1 = ((256 + tid) & 3) ^ ((srow1 >> 2) & 3);

  f32x4 acc[4][4] = {};

  // stage K-step 0 -> buf 0 (async DMA)
  {
    char* sa0 = smem;
    char* sb0 = smem + 16384;
    gload16(xb + (size_t)(m0 + srow0) * 1024 + schs0 * 8, sa0 + tid * 16);
    gload16(wt + (size_t)(n0 + srow0) * 1024 + schs0 * 8, sb0 + tid * 16);
    gload16(xb + (size_t)(m0 + srow1) * 1024 + schs1 * 8, sa0 + 4096 + tid * 16);
    gload16(wt + (size_t)(n0 + srow1) * 1024 + schs1 * 8, sb0 + 4096 + tid * 16);
  }

  #pragma unroll 1
  for(int kt = 0; kt < 32; kt++){
    const int cur = kt & 1;
    char* saC = smem + cur * 8192;             // current A buf
    char* sbC = smem + 16384 + cur * 8192;     // current B buf
    char* saN = smem + (cur ^ 1) * 8192;       // next A buf
    char* sbN = smem + 16384 + (cur ^ 1) * 8192;
    __syncthreads();               // drains vmcnt: buf[cur] ready; buf[cur^1] readers done

    if(kt + 1 < 32){
      const int k0n = (kt + 1) * 32;
      gload16(xb + (size_t)(m0 + srow0) * 1024 + k0n + schs0 * 8, saN + tid * 16);
      gload16(wt + (size_t)(n0 + srow0) * 1024 + k0n + schs0 * 8, sbN + tid * 16);
      gload16(xb + (size_t)(m0 + srow1) * 1024 + k0n + schs1 * 8, saN + 4096 + tid * 16);
      gload16(wt + (size_t)(n0 + srow1) * 1024 + k0n + schs1 * 8, sbN + 4096 + tid * 16);
    }

    short8 af[4], bfr[4];
    #pragma unroll
    for(int i = 0; i < 4; i++){
      int ra = wm + i * 16 + ln16;
      af[i] = *(const short8*)(saC + ra * 64 + ((hi ^ ((ra >> 2) & 3)) << 4));
      int rb = wn + i * 16 + ln16;
      bfr[i] = *(const short8*)(sbC + rb * 64 + ((hi ^ ((rb >> 2) & 3)) << 4));
    }
    __builtin_amdgcn_s_setprio(1);
    #pragma unroll
    for(int i = 0; i < 4; i++)
      #pragma unroll
      for(int j = 0; j < 4; j++)
        acc[i][j] = MFMA(af[i], bfr[j], acc[i][j]);
    __builtin_amdgcn_s_setprio(0);
  }

  const float scl = (mat == 0) ? QSCALE : 1.0f;
  #pragma unroll
  for(int j = 0; j < 4; j++){
    int n = n0 + wn + j * 16 + ln16;
    float bv_ = bias[n];
    int h = n >> 6, d = n & 63;
    #pragma unroll
    for(int i = 0; i < 4; i++){
      int mb = m0 + wm + i * 16 + hi * 4;
      int b = mb >> 11, t = mb & 2047;
      int bh = b * NH + h;
      if(mat == 2){
        // V^T store, KEY-PERMUTED within each 32-key group (attn PV b128 reads)
        ushort4 o4;
        o4.x = f2bf(acc[i][j][0] + bv_);
        o4.y = f2bf(acc[i][j][1] + bv_);
        o4.z = f2bf(acc[i][j][2] + bv_);
        o4.w = f2bf(acc[i][j][3] + bv_);
        int tp = (t & ~31) | (((t >> 2) & 3) << 3) | (((t >> 4) & 1) << 2);
        *(ushort4*)(vtws + ((size_t)bh * DK + d) * TT + tp) = o4;
      } else {
        u16* dst = (mat == 0) ? qws : kws;
        #pragma unroll
        for(int r = 0; r < 4; r++){
          u16 o = f2bf((acc[i][j][r] + bv_) * scl);
          dst[((size_t)bh * TT + t + r) * DK + d] = o;
        }
      }
    }
  }
}

// ---------------- flash attention (R6-verified: 8-wave, paired, 16 waves/CU) ----------------
// 8-wave blocks, 128 q-rows per q-tile; per-tile fixed costs amortized over 2x
// q-rows. Grid 512, bijective XCD swizzle (XCD k owns bh in [8k,8k+8), 4MB = its
// L2); pairs (x, 15-x) -> every block runs exactly 34 k-iterations (balanced —
// R2/R9 lesson: imbalance poisons occupancy). 2 blocks/CU x 8 waves = 16
// waves/CU (R8 lesson: the win condition is >=16 waves/CU). Lower 4 waves skip
// their fully-masked final k-tile. VGPR ~56 (< 64 cliff — R3 lesson).
// At ~97% of the LDS-service model — attn structural ceiling for this session
// (32x32 core R8 and dual-subtile reuse R9 both regressed).
__global__ __launch_bounds__(512) void attn(
    const u16* __restrict__ qws, const u16* __restrict__ kws, const u16* __restrict__ vtws,
    float* __restrict__ out){
  __shared__ u16 kt[2][64 * 64];    // [buf][key][d]  swizzled
  __shared__ u16 vt[2][64 * 64];    // [buf][d][key-permuted]  swizzled

  const int id = blockIdx.x;
  const int swz = (id & 7) * 64 + (id >> 3);   // bijective (512 % 8 == 0)
  const int qx = swz & 7;                      // pair index 0..7
  const int bh = swz >> 3;

  const int tid = threadIdx.x, lane = tid & 63, w = tid >> 6;   // w 0..7
  const int g = lane >> 4, ln = lane & 15;
  const int b = bh >> 4, h = bh & 15;
  const u16* kbase = kws + (size_t)bh * TT * DK;
  const u16* vbase = vtws + (size_t)bh * DK * TT;
  const int sbase = tid & 448;      // wave-uniform 16B-chunk base (HW adds lane*16)
  const int srow = tid >> 3;        // staging row 0..63
  const int schs = (tid & 7) ^ (srow & 7);     // inverse swizzle on the SOURCE

  #pragma unroll 1
  for(int qi = 0; qi < 2; qi++){
    const int qt = qi ? (15 - qx) : qx;        // 128-row q-tile 0..15
    const int q = qt * 128 + w * 16 + ln;      // this lane's q row

    // Q fragment (B-operand; pre-scaled by QSCALE): k-slots d = g*8+j (+32)
    short8 qf[2];
    {
      const u16* gq = qws + ((size_t)bh * TT + q) * DK + g * 8;
      qf[0] = *(const short8*)gq;
      qf[1] = *(const short8*)(gq + 32);
    }

    f32x4 o[4] = {};                 // O^T frags: o[i][r] = O^T[d=i*16+g*4+r][q]
    float m = -INFINITY, l = 0.f;    // l: per-lane partial sum (reduced in epilogue)

    const int nkt = 2 * qt + 2;            // block-level 64-key tiles
    const int myNkt = nkt - (w < 4 ? 1 : 0);  // lower waves: last tile fully masked

    __syncthreads();                 // prev q-tile readers done; no DMAs outstanding
    // stage k-tile 0 -> buf 0 (async DMA; 512 threads cover 64x64 in one pass)
    gload16(kbase + (size_t)srow * DK + schs * 8, (char*)kt[0] + sbase * 16);
    gload16(vbase + (size_t)srow * TT + schs * 8, (char*)vt[0] + sbase * 16);

    #pragma unroll 1
    for(int kti = 0; kti < nkt; kti++){
      const int cur = kti & 1;
      __syncthreads();               // drains vmcnt: buf[cur] ready; buf[cur^1] readers done

      // async-prefetch next tile straight into buf[cur^1] (drained at next barrier)
      if(kti + 1 < nkt){
        const int k0n = (kti + 1) * 64;
        gload16(kbase + (size_t)(k0n + srow) * DK + schs * 8, (char*)kt[cur ^ 1] + sbase * 16);
        gload16(vbase + (size_t)srow * TT + k0n + schs * 8, (char*)vt[cur ^ 1] + sbase * 16);
      }

      if(kti < myNkt){
        // S^T = K Q : s[i][r] = S[key = k0+i*16+g*4+r][q]
        f32x4 s[4];
        __builtin_amdgcn_s_setprio(1);
        #pragma unroll
        for(int i = 0; i < 4; i++){
          f32x4 c = {};
          #pragma unroll
          for(int ks = 0; ks < 2; ks++){
            int rb = i * 16 + ln;
            int cb = ks * 64 + g * 16;
            short8 kfr = *(const short8*)((const char*)kt[cur] + rb * 128 + (cb ^ ((rb & 7) << 4)));
            c = MFMA(kfr, qf[ks], c);
          }
          s[i] = c;
        }
        __builtin_amdgcn_s_setprio(0);

        if(kti == myNkt - 1){          // causal mask (this wave's diagonal tile)
          const int k0 = kti * 64;
          #pragma unroll
          for(int i = 0; i < 4; i++)
            #pragma unroll
            for(int r = 0; r < 4; r++)
              if(k0 + i * 16 + g * 4 + r > q) s[i][r] = -INFINITY;
        }

        // in-register row max (16 regs) + cross-group permlane swaps (full row = 4 groups)
        float mx0 = fmaxf(fmaxf(s[0][0], s[0][1]), fmaxf(s[0][2], s[0][3]));
        float mx1 = fmaxf(fmaxf(s[1][0], s[1][1]), fmaxf(s[1][2], s[1][3]));
        float mx2 = fmaxf(fmaxf(s[2][0], s[2][1]), fmaxf(s[2][2], s[2][3]));
        float mx3 = fmaxf(fmaxf(s[3][0], s[3][1]), fmaxf(s[3][2], s[3][3]));
        float pmax = fmaxf(fmaxf(mx0, mx1), fmaxf(mx2, mx3));
        pmax = plmax(pmax);

        // defer-max (T13): skip O-rescale when per-tile max growth <= 8 (exp2 domain)
        if(!__all(pmax <= m + 8.f)){
          float mnew = fmaxf(m, pmax);
          float alpha = EXP2(m - mnew);
          l *= alpha;
          #pragma unroll
          for(int i = 0; i < 4; i++)
            #pragma unroll
            for(int r = 0; r < 4; r++) o[i][r] *= alpha;
          m = mnew;
        }

        #pragma unroll
        for(int i = 0; i < 4; i++)
          #pragma unroll
          for(int r = 0; r < 4; r++){
            float p = EXP2(s[i][r] - m);
            s[i][r] = p; l += p;        // per-lane partial only
          }

        // pack P to bf16 B-frags in-register: pb[ks] reg j holds key kappa(g,j)+32ks
        union PU { short8 s8; unsigned w[4]; };
        PU pb[2];
        #pragma unroll
        for(int ks = 0; ks < 2; ks++){
          pb[ks].w[0] = cvtpk(s[2*ks][0],   s[2*ks][1]);
          pb[ks].w[1] = cvtpk(s[2*ks][2],   s[2*ks][3]);
          pb[ks].w[2] = cvtpk(s[2*ks+1][0], s[2*ks+1][1]);
          pb[ks].w[3] = cvtpk(s[2*ks+1][2], s[2*ks+1][3]);
        }

        // O^T += V^T P^T : key-permuted vt makes each A-frag ONE swizzled b128 read
        __builtin_amdgcn_s_setprio(1);
        #pragma unroll
        for(int i = 0; i < 4; i++){
          int dr = i * 16 + ln;
          const char* vrow = (const char*)vt[cur] + dr * 128;
          int sw = (dr & 7) << 4;
          #pragma unroll
          for(int ks = 0; ks < 2; ks++){
            short8 av = *(const short8*)(vrow + ((64 * ks + g * 16) ^ sw));
            o[i] = MFMA(av, pb[ks].s8, o[i]);
          }
        }
        __builtin_amdgcn_s_setprio(0);
      }
    }

    // epilogue: deferred l reduce, then out (B,T,DM) fp32, float4 stores
    l = plsum(l);
    float inv = 1.0f / l;
    float* orow = out + ((size_t)(b * TT + q)) * DM + h * 64 + g * 4;
    #pragma unroll
    for(int i = 0; i < 4; i++){
      float4 v4;
      v4.x = o[i][0] * inv; v4.y = o[i][1] * inv;
      v4.z = o[i][2] * inv; v4.w = o[i][3] * inv;
      *(float4*)(orow + i * 16) = v4;
    }
  }
}

extern "C" void kernel_launch(void* const* d_in, const int* in_sizes, int n_in,
                              void* d_out, int out_size, void* d_ws, size_t ws_size,
                              hipStream_t stream){
  const float* x  = (const float*)d_in[0];
  const float* Wq = (const float*)d_in[1];
  const float* bq = (const float*)d_in[2];
  const float* Wk = (const float*)d_in[3];
  const float* bk = (const float*)d_in[4];
  const float* Wv = (const float*)d_in[5];
  const float* bv = (const float*)d_in[6];
  float* out = (float*)d_out;

  char* ws = (char*)d_ws;
  u16* xb   = (u16*)(ws);                       // 16 MB  x bf16 (M,K)
  u16* wtq  = (u16*)(ws + (16u << 20));         //  2 MB  Wq^T bf16 (N,K)
  u16* wtk  = (u16*)(ws + (18u << 20));
  u16* wtv  = (u16*)(ws + (20u << 20));
  u16* qws  = (u16*)(ws + (22u << 20));         // 16 MB  Q (BH,T,DK) bf16 (pre-scaled)
  u16* kws  = (u16*)(ws + (38u << 20));         // 16 MB  K (BH,T,DK) bf16
  u16* vtws = (u16*)(ws + (54u << 20));         // 16 MB  V^T (BH,DK,T) bf16, key-permuted

  static bool qkv_init = false;
  if(!qkv_init){
    (void)hipFuncSetAttribute((const void*)qkv_gemm,
                              hipFuncAttributeMaxDynamicSharedMemorySize, 49152);
    qkv_init = true;
  }

  prep<<<dim3(8192 + 3072), dim3(256), 0, stream>>>(x, xb, Wq, Wk, Wv, wtq, wtk, wtv);
  qkv_gemm<<<dim3(1536), dim3(256), 49152, stream>>>(xb, wtq, wtk, wtv, bq, bk, bv, qws, kws, vtws);
  attn<<<dim3(512), dim3(512), 0, stream>>>(qws, kws, vtws, out);
}

// Round 14
// 141.274 us; speedup vs baseline: 1.0649x; 1.0649x over previous
//
#include <hip/hip_runtime.h>
#include <hip/hip_bf16.h>

#define DM 1024
#define NH 16
#define DK 64
#define TT 2048
#define NBATCH 4
#define BT 8192   // NBATCH*TT

typedef __attribute__((ext_vector_type(8))) short short8;
typedef __attribute__((ext_vector_type(4))) float f32x4;
typedef unsigned short u16;

#define MFMA(a,b,c) __builtin_amdgcn_mfma_f32_16x16x32_bf16((a),(b),(c),0,0,0)

// 1/sqrt(64) * log2(e): folded into Q so attn softmax can use exp2 directly
#define QSCALE 0.18033688011112684f

// raw v_exp_f32 (flush-denorm fine for softmax), skips OCML fixup code
#define EXP2(x) __builtin_amdgcn_exp2f(x)

__device__ __forceinline__ u16 f2bf(float f){
  union { float f; unsigned u; } v; v.f = f;
  return (u16)((v.u + 0x7fffu + ((v.u >> 16) & 1u)) >> 16);
}

__device__ __forceinline__ unsigned cvtpk(float lo, float hi){
  unsigned r;
  asm("v_cvt_pk_bf16_f32 %0, %1, %2" : "=v"(r) : "v"(lo), "v"(hi));
  return r;
}

// async global->LDS DMA, 16B/lane. LDS dest must be wave-uniform base (+lane*16).
__device__ __forceinline__ void gload16(const void* g, void* l){
  __builtin_amdgcn_global_load_lds((__attribute__((address_space(1))) void*)(g),
                                   (__attribute__((address_space(3))) void*)(l), 16, 0, 0);
}

// cross-lane reduce over the 4 16-lane groups (lane ^16, ^32): pure-VALU permlanes
__device__ __forceinline__ float plmax(float x){
#if __has_builtin(__builtin_amdgcn_permlane16_swap) && __has_builtin(__builtin_amdgcn_permlane32_swap)
  auto r = __builtin_amdgcn_permlane16_swap(__float_as_uint(x), __float_as_uint(x), false, false);
  x = fmaxf(__uint_as_float(r[0]), __uint_as_float(r[1]));
  auto r2 = __builtin_amdgcn_permlane32_swap(__float_as_uint(x), __float_as_uint(x), false, false);
  x = fmaxf(__uint_as_float(r2[0]), __uint_as_float(r2[1]));
#else
  x = fmaxf(x, __shfl_xor(x, 16, 64));
  x = fmaxf(x, __shfl_xor(x, 32, 64));
#endif
  return x;
}

__device__ __forceinline__ float plsum(float x){
#if __has_builtin(__builtin_amdgcn_permlane16_swap) && __has_builtin(__builtin_amdgcn_permlane32_swap)
  auto r = __builtin_amdgcn_permlane16_swap(__float_as_uint(x), __float_as_uint(x), false, false);
  x = __uint_as_float(r[0]) + __uint_as_float(r[1]);
  auto r2 = __builtin_amdgcn_permlane32_swap(__float_as_uint(x), __float_as_uint(x), false, false);
  x = __uint_as_float(r2[0]) + __uint_as_float(r2[1]);
#else
  x = x + __shfl_xor(x, 16, 64);
  x = x + __shfl_xor(x, 32, 64);
#endif
  return x;
}

// ---------------- prep: x fp32->bf16  +  W (K,N) fp32 -> wt (N,K) bf16 ----------------
// merged single launch (block-uniform branch): blocks [0,8192) convert x,
// blocks [8192, 8192+3072) transpose+convert the three weight matrices.
__global__ __launch_bounds__(256) void prep(
    const float* __restrict__ x, u16* __restrict__ xb,
    const float* __restrict__ Wq, const float* __restrict__ Wk, const float* __restrict__ Wv,
    u16* __restrict__ wtq, u16* __restrict__ wtk, u16* __restrict__ wtv){
  __shared__ float tile[32][33];
  const int id = blockIdx.x;
  if(id < 8192){
    int i = (id * 256 + threadIdx.x) * 4;
    float4 v = *(const float4*)(x + i);
    ushort4 o; o.x = f2bf(v.x); o.y = f2bf(v.y); o.z = f2bf(v.z); o.w = f2bf(v.w);
    *(ushort4*)(xb + i) = o;
  } else {
    int r3 = id - 8192;                 // 0..3071
    int z = r3 >> 10;                   // 0..2
    int rem = r3 & 1023;
    int bx = rem & 31, by = rem >> 5;
    const float* W = (z == 0) ? Wq : (z == 1) ? Wk : Wv;
    u16* wt = (z == 0) ? wtq : (z == 1) ? wtk : wtv;
    int k0 = bx * 32, n0 = by * 32;
    int tx = threadIdx.x & 31, ty = threadIdx.x >> 5;
    #pragma unroll
    for(int r = ty; r < 32; r += 8)
      tile[r][tx] = W[(size_t)(k0 + r) * DM + n0 + tx];
    __syncthreads();
    #pragma unroll
    for(int r = ty; r < 32; r += 8)
      wt[(size_t)(n0 + r) * DM + k0 + tx] = f2bf(tile[tx][r]);
  }
}

// ---------------- QKV projection GEMM (session-verified best: 2-phase dbuf, 72us) ----------------
// 128x128 tile, BK=64, 4 waves; global_load_lds staging (linear dest, inverse-
// swizzled source); double-buffered: prefetch t+1 issued after the barrier,
// drained at the NEXT barrier. XCD-locality 1-D grid: XCD k owns M-tiles
// [8k,8k+8) (2MB of xb, L2-resident), weight panels m-inner (panel L2-hot).
// V^T store KEY-PERMUTED (attn PV: key 16*hi+4*g+r -> pos 8*g+4*hi+r).
// Closed levers (all regressed vs this config): 8-phase 256^2 (R7, dispatch
// tail + epilogue), A-direct-from-L2 (R10, uncoalesced + drain), BK=32 smaller
// tile (R13, occupancy did NOT rise — limiter isn't LDS — and swizzle conflicts).
__global__ __launch_bounds__(256) void qkv_gemm(
    const u16* __restrict__ xb,
    const u16* __restrict__ wtq, const u16* __restrict__ wtk, const u16* __restrict__ wtv,
    const float* __restrict__ bq, const float* __restrict__ bk, const float* __restrict__ bv,
    u16* __restrict__ qws, u16* __restrict__ kws, u16* __restrict__ vtws){
  __shared__ u16 sa[2][128 * 64];
  __shared__ u16 sb[2][128 * 64];
  const int id = blockIdx.x;              // 0..1535
  const int idx = id >> 3;                // 0..191 within XCD
  const int mt = (id & 7) * 8 + (idx & 7);// M-tile 0..63
  const int y  = idx >> 3;                // weight panel 0..23
  const int m0 = mt * 128;
  const int ng = y * 128;
  const int mat = ng >> 10;
  const int n0 = ng & 1023;
  const u16* wt = (mat == 0) ? wtq : (mat == 1) ? wtk : wtv;
  const float* bias = (mat == 0) ? bq : (mat == 1) ? bk : bv;
  const int tid = threadIdx.x;
  const int lane = tid & 63, w = tid >> 6;
  const int wm = (w >> 1) * 64, wn = (w & 1) * 64;
  const int wbase0 = tid & 192;   // w*64, wave-uniform

  f32x4 acc[4][4] = {};

  // stage K-tile 0 -> buf 0 (async DMA)
  #pragma unroll
  for(int p = 0; p < 4; p++){
    int base = p * 256 + wbase0;
    int idx2 = base + lane;
    int row = idx2 >> 3;
    int chs = (idx2 & 7) ^ (row & 7);
    gload16(xb + (size_t)(m0 + row) * 1024 + chs * 8, (char*)sa[0] + base * 16);
    gload16(wt + (size_t)(n0 + row) * 1024 + chs * 8, (char*)sb[0] + base * 16);
  }

  #pragma unroll 1
  for(int kt = 0; kt < 16; kt++){
    const int cur = kt & 1;
    __syncthreads();               // drains vmcnt: buf[cur] ready; buf[cur^1] readers done

    if(kt + 1 < 16){
      const int k0n = (kt + 1) * 64;
      #pragma unroll
      for(int p = 0; p < 4; p++){
        int base = p * 256 + wbase0;
        int idx2 = base + lane;
        int row = idx2 >> 3;
        int chs = (idx2 & 7) ^ (row & 7);
        gload16(xb + (size_t)(m0 + row) * 1024 + k0n + chs * 8, (char*)sa[cur ^ 1] + base * 16);
        gload16(wt + (size_t)(n0 + row) * 1024 + k0n + chs * 8, (char*)sb[cur ^ 1] + base * 16);
      }
    }

    #pragma unroll
    for(int ks = 0; ks < 2; ks++){
      short8 af[4], bfr[4];
      #pragma unroll
      for(int i = 0; i < 4; i++){
        int ra = wm + i * 16 + (lane & 15);
        int ca = ks * 64 + (lane >> 4) * 16;
        af[i] = *(const short8*)((const char*)sa[cur] + ra * 128 + (ca ^ ((ra & 7) << 4)));
        int rb = wn + i * 16 + (lane & 15);
        bfr[i] = *(const short8*)((const char*)sb[cur] + rb * 128 + (ca ^ ((rb & 7) << 4)));
      }
      __builtin_amdgcn_s_setprio(1);
      #pragma unroll
      for(int i = 0; i < 4; i++)
        #pragma unroll
        for(int j = 0; j < 4; j++)
          acc[i][j] = MFMA(af[i], bfr[j], acc[i][j]);
      __builtin_amdgcn_s_setprio(0);
    }
  }

  const float scl = (mat == 0) ? QSCALE : 1.0f;
  #pragma unroll
  for(int j = 0; j < 4; j++){
    int n = n0 + wn + j * 16 + (lane & 15);
    float bv_ = bias[n];
    int h = n >> 6, d = n & 63;
    #pragma unroll
    for(int i = 0; i < 4; i++){
      int mb = m0 + wm + i * 16 + (lane >> 4) * 4;
      int b = mb >> 11, t = mb & 2047;
      int bh = b * NH + h;
      if(mat == 2){
        // V^T store, KEY-PERMUTED within each 32-key group (attn PV b128 reads)
        ushort4 o4;
        o4.x = f2bf(acc[i][j][0] + bv_);
        o4.y = f2bf(acc[i][j][1] + bv_);
        o4.z = f2bf(acc[i][j][2] + bv_);
        o4.w = f2bf(acc[i][j][3] + bv_);
        int tp = (t & ~31) | (((t >> 2) & 3) << 3) | (((t >> 4) & 1) << 2);
        *(ushort4*)(vtws + ((size_t)bh * DK + d) * TT + tp) = o4;
      } else {
        u16* dst = (mat == 0) ? qws : kws;
        #pragma unroll
        for(int r = 0; r < 4; r++){
          u16 o = f2bf((acc[i][j][r] + bv_) * scl);
          dst[((size_t)bh * TT + t + r) * DK + d] = o;
        }
      }
    }
  }
}

// ---------------- flash attention (session-verified best: 8-wave, paired, 16 waves/CU) ----------------
// 8-wave blocks, 128 q-rows per q-tile; per-tile fixed costs amortized over 2x
// q-rows. Grid 512, bijective XCD swizzle (XCD k owns bh in [8k,8k+8), 4MB = its
// L2; FETCH 228MB -> 24.6MB); pairs (x, 15-x) -> every block runs exactly 34
// k-iterations (balanced — R2/R9 lesson: imbalance poisons occupancy). 2
// blocks/CU x 8 waves = 16 waves/CU (R8 lesson: the win condition is >=16
// waves/CU). Lower 4 waves skip their fully-masked final k-tile. VGPR ~56
// (< 64 cliff — R3 lesson). Key-permuted V^T -> conflict-free PV b128 reads
// (R2-verified: SQ_LDS_BANK_CONFLICT 8.65M -> 0). At ~97% of the LDS-service
// model — structural ceiling (32x32 core R8, dual-subtile R9 both regressed).
__global__ __launch_bounds__(512) void attn(
    const u16* __restrict__ qws, const u16* __restrict__ kws, const u16* __restrict__ vtws,
    float* __restrict__ out){
  __shared__ u16 kt[2][64 * 64];    // [buf][key][d]  swizzled
  __shared__ u16 vt[2][64 * 64];    // [buf][d][key-permuted]  swizzled

  const int id = blockIdx.x;
  const int swz = (id & 7) * 64 + (id >> 3);   // bijective (512 % 8 == 0)
  const int qx = swz & 7;                      // pair index 0..7
  const int bh = swz >> 3;

  const int tid = threadIdx.x, lane = tid & 63, w = tid >> 6;   // w 0..7
  const int g = lane >> 4, ln = lane & 15;
  const int b = bh >> 4, h = bh & 15;
  const u16* kbase = kws + (size_t)bh * TT * DK;
  const u16* vbase = vtws + (size_t)bh * DK * TT;
  const int sbase = tid & 448;      // wave-uniform 16B-chunk base (HW adds lane*16)
  const int srow = tid >> 3;        // staging row 0..63
  const int schs = (tid & 7) ^ (srow & 7);     // inverse swizzle on the SOURCE

  #pragma unroll 1
  for(int qi = 0; qi < 2; qi++){
    const int qt = qi ? (15 - qx) : qx;        // 128-row q-tile 0..15
    const int q = qt * 128 + w * 16 + ln;      // this lane's q row

    // Q fragment (B-operand; pre-scaled by QSCALE): k-slots d = g*8+j (+32)
    short8 qf[2];
    {
      const u16* gq = qws + ((size_t)bh * TT + q) * DK + g * 8;
      qf[0] = *(const short8*)gq;
      qf[1] = *(const short8*)(gq + 32);
    }

    f32x4 o[4] = {};                 // O^T frags: o[i][r] = O^T[d=i*16+g*4+r][q]
    float m = -INFINITY, l = 0.f;    // l: per-lane partial sum (reduced in epilogue)

    const int nkt = 2 * qt + 2;            // block-level 64-key tiles
    const int myNkt = nkt - (w < 4 ? 1 : 0);  // lower waves: last tile fully masked

    __syncthreads();                 // prev q-tile readers done; no DMAs outstanding
    // stage k-tile 0 -> buf 0 (async DMA; 512 threads cover 64x64 in one pass)
    gload16(kbase + (size_t)srow * DK + schs * 8, (char*)kt[0] + sbase * 16);
    gload16(vbase + (size_t)srow * TT + schs * 8, (char*)vt[0] + sbase * 16);

    #pragma unroll 1
    for(int kti = 0; kti < nkt; kti++){
      const int cur = kti & 1;
      __syncthreads();               // drains vmcnt: buf[cur] ready; buf[cur^1] readers done

      // async-prefetch next tile straight into buf[cur^1] (drained at next barrier)
      if(kti + 1 < nkt){
        const int k0n = (kti + 1) * 64;
        gload16(kbase + (size_t)(k0n + srow) * DK + schs * 8, (char*)kt[cur ^ 1] + sbase * 16);
        gload16(vbase + (size_t)srow * TT + k0n + schs * 8, (char*)vt[cur ^ 1] + sbase * 16);
      }

      if(kti < myNkt){
        // S^T = K Q : s[i][r] = S[key = k0+i*16+g*4+r][q]
        f32x4 s[4];
        __builtin_amdgcn_s_setprio(1);
        #pragma unroll
        for(int i = 0; i < 4; i++){
          f32x4 c = {};
          #pragma unroll
          for(int ks = 0; ks < 2; ks++){
            int rb = i * 16 + ln;
            int cb = ks * 64 + g * 16;
            short8 kfr = *(const short8*)((const char*)kt[cur] + rb * 128 + (cb ^ ((rb & 7) << 4)));
            c = MFMA(kfr, qf[ks], c);
          }
          s[i] = c;
        }
        __builtin_amdgcn_s_setprio(0);

        if(kti == myNkt - 1){          // causal mask (this wave's diagonal tile)
          const int k0 = kti * 64;
          #pragma unroll
          for(int i = 0; i < 4; i++)
            #pragma unroll
            for(int r = 0; r < 4; r++)
              if(k0 + i * 16 + g * 4 + r > q) s[i][r] = -INFINITY;
        }

        // in-register row max (16 regs) + cross-group permlane swaps (full row = 4 groups)
        float mx0 = fmaxf(fmaxf(s[0][0], s[0][1]), fmaxf(s[0][2], s[0][3]));
        float mx1 = fmaxf(fmaxf(s[1][0], s[1][1]), fmaxf(s[1][2], s[1][3]));
        float mx2 = fmaxf(fmaxf(s[2][0], s[2][1]), fmaxf(s[2][2], s[2][3]));
        float mx3 = fmaxf(fmaxf(s[3][0], s[3][1]), fmaxf(s[3][2], s[3][3]));
        float pmax = fmaxf(fmaxf(mx0, mx1), fmaxf(mx2, mx3));
        pmax = plmax(pmax);

        // defer-max (T13): skip O-rescale when per-tile max growth <= 8 (exp2 domain)
        if(!__all(pmax <= m + 8.f)){
          float mnew = fmaxf(m, pmax);
          float alpha = EXP2(m - mnew);
          l *= alpha;
          #pragma unroll
          for(int i = 0; i < 4; i++)
            #pragma unroll
            for(int r = 0; r < 4; r++) o[i][r] *= alpha;
          m = mnew;
        }

        #pragma unroll
        for(int i = 0; i < 4; i++)
          #pragma unroll
          for(int r = 0; r < 4; r++){
            float p = EXP2(s[i][r] - m);
            s[i][r] = p; l += p;        // per-lane partial only
          }

        // pack P to bf16 B-frags in-register: pb[ks] reg j holds key kappa(g,j)+32ks
        union PU { short8 s8; unsigned w[4]; };
        PU pb[2];
        #pragma unroll
        for(int ks = 0; ks < 2; ks++){
          pb[ks].w[0] = cvtpk(s[2*ks][0],   s[2*ks][1]);
          pb[ks].w[1] = cvtpk(s[2*ks][2],   s[2*ks][3]);
          pb[ks].w[2] = cvtpk(s[2*ks+1][0], s[2*ks+1][1]);
          pb[ks].w[3] = cvtpk(s[2*ks+1][2], s[2*ks+1][3]);
        }

        // O^T += V^T P^T : key-permuted vt makes each A-frag ONE swizzled b128 read
        __builtin_amdgcn_s_setprio(1);
        #pragma unroll
        for(int i = 0; i < 4; i++){
          int dr = i * 16 + ln;
          const char* vrow = (const char*)vt[cur] + dr * 128;
          int sw = (dr & 7) << 4;
          #pragma unroll
          for(int ks = 0; ks < 2; ks++){
            short8 av = *(const short8*)(vrow + ((64 * ks + g * 16) ^ sw));
            o[i] = MFMA(av, pb[ks].s8, o[i]);
          }
        }
        __builtin_amdgcn_s_setprio(0);
      }
    }

    // epilogue: deferred l reduce, then out (B,T,DM) fp32, float4 stores
    l = plsum(l);
    float inv = 1.0f / l;
    float* orow = out + ((size_t)(b * TT + q)) * DM + h * 64 + g * 4;
    #pragma unroll
    for(int i = 0; i < 4; i++){
      float4 v4;
      v4.x = o[i][0] * inv; v4.y = o[i][1] * inv;
      v4.z = o[i][2] * inv; v4.w = o[i][3] * inv;
      *(float4*)(orow + i * 16) = v4;
    }
  }
}

extern "C" void kernel_launch(void* const* d_in, const int* in_sizes, int n_in,
                              void* d_out, int out_size, void* d_ws, size_t ws_size,
                              hipStream_t stream){
  const float* x  = (const float*)d_in[0];
  const float* Wq = (const float*)d_in[1];
  const float* bq = (const float*)d_in[2];
  const float* Wk = (const float*)d_in[3];
  const float* bk = (const float*)d_in[4];
  const float* Wv = (const float*)d_in[5];
  const float* bv = (const float*)d_in[6];
  float* out = (float*)d_out;

  char* ws = (char*)d_ws;
  u16* xb   = (u16*)(ws);                       // 16 MB  x bf16 (M,K)
  u16* wtq  = (u16*)(ws + (16u << 20));         //  2 MB  Wq^T bf16 (N,K)
  u16* wtk  = (u16*)(ws + (18u << 20));
  u16* wtv  = (u16*)(ws + (20u << 20));
  u16* qws  = (u16*)(ws + (22u << 20));         // 16 MB  Q (BH,T,DK) bf16 (pre-scaled)
  u16* kws  = (u16*)(ws + (38u << 20));         // 16 MB  K (BH,T,DK) bf16
  u16* vtws = (u16*)(ws + (54u << 20));         // 16 MB  V^T (BH,DK,T) bf16, key-permuted

  prep<<<dim3(8192 + 3072), dim3(256), 0, stream>>>(x, xb, Wq, Wk, Wv, wtq, wtk, wtv);
  qkv_gemm<<<dim3(1536), dim3(256), 0, stream>>>(xb, wtq, wtk, wtv, bq, bk, bv, qws, kws, vtws);
  attn<<<dim3(512), dim3(512), 0, stream>>>(qws, kws, vtws, out);
}

// Round 15
// 133.063 us; speedup vs baseline: 1.1306x; 1.0617x over previous
//
#include <hip/hip_runtime.h>
#include <hip/hip_bf16.h>

#define DM 1024
#define NH 16
#define DK 64
#define TT 2048
#define NBATCH 4
#define BT 8192   // NBATCH*TT

typedef __attribute__((ext_vector_type(8))) short short8;
typedef __attribute__((ext_vector_type(4))) float f32x4;
typedef unsigned short u16;

#define MFMA(a,b,c) __builtin_amdgcn_mfma_f32_16x16x32_bf16((a),(b),(c),0,0,0)

// 1/sqrt(64) * log2(e): folded into Q so attn softmax can use exp2 directly
#define QSCALE 0.18033688011112684f

// raw v_exp_f32 (flush-denorm fine for softmax), skips OCML fixup code
#define EXP2(x) __builtin_amdgcn_exp2f(x)

__device__ __forceinline__ u16 f2bf(float f){
  union { float f; unsigned u; } v; v.f = f;
  return (u16)((v.u + 0x7fffu + ((v.u >> 16) & 1u)) >> 16);
}

__device__ __forceinline__ unsigned cvtpk(float lo, float hi){
  unsigned r;
  asm("v_cvt_pk_bf16_f32 %0, %1, %2" : "=v"(r) : "v"(lo), "v"(hi));
  return r;
}

// async global->LDS DMA, 16B/lane. LDS dest must be wave-uniform base (+lane*16).
__device__ __forceinline__ void gload16(const void* g, void* l){
  __builtin_amdgcn_global_load_lds((__attribute__((address_space(1))) void*)(g),
                                   (__attribute__((address_space(3))) void*)(l), 16, 0, 0);
}

// cross-lane reduce over the 4 16-lane groups (lane ^16, ^32): pure-VALU permlanes
__device__ __forceinline__ float plmax(float x){
#if __has_builtin(__builtin_amdgcn_permlane16_swap) && __has_builtin(__builtin_amdgcn_permlane32_swap)
  auto r = __builtin_amdgcn_permlane16_swap(__float_as_uint(x), __float_as_uint(x), false, false);
  x = fmaxf(__uint_as_float(r[0]), __uint_as_float(r[1]));
  auto r2 = __builtin_amdgcn_permlane32_swap(__float_as_uint(x), __float_as_uint(x), false, false);
  x = fmaxf(__uint_as_float(r2[0]), __uint_as_float(r2[1]));
#else
  x = fmaxf(x, __shfl_xor(x, 16, 64));
  x = fmaxf(x, __shfl_xor(x, 32, 64));
#endif
  return x;
}

__device__ __forceinline__ float plsum(float x){
#if __has_builtin(__builtin_amdgcn_permlane16_swap) && __has_builtin(__builtin_amdgcn_permlane32_swap)
  auto r = __builtin_amdgcn_permlane16_swap(__float_as_uint(x), __float_as_uint(x), false, false);
  x = __uint_as_float(r[0]) + __uint_as_float(r[1]);
  auto r2 = __builtin_amdgcn_permlane32_swap(__float_as_uint(x), __float_as_uint(x), false, false);
  x = __uint_as_float(r2[0]) + __uint_as_float(r2[1]);
#else
  x = x + __shfl_xor(x, 16, 64);
  x = x + __shfl_xor(x, 32, 64);
#endif
  return x;
}

// ---------------- prep: x fp32->bf16  +  W (K,N) fp32 -> wt (N,K) bf16 ----------------
// merged single launch (block-uniform branch): blocks [0,8192) convert x,
// blocks [8192, 8192+3072) transpose+convert the three weight matrices.
__global__ __launch_bounds__(256) void prep(
    const float* __restrict__ x, u16* __restrict__ xb,
    const float* __restrict__ Wq, const float* __restrict__ Wk, const float* __restrict__ Wv,
    u16* __restrict__ wtq, u16* __restrict__ wtk, u16* __restrict__ wtv){
  __shared__ float tile[32][33];
  const int id = blockIdx.x;
  if(id < 8192){
    int i = (id * 256 + threadIdx.x) * 4;
    float4 v = *(const float4*)(x + i);
    ushort4 o; o.x = f2bf(v.x); o.y = f2bf(v.y); o.z = f2bf(v.z); o.w = f2bf(v.w);
    *(ushort4*)(xb + i) = o;
  } else {
    int r3 = id - 8192;                 // 0..3071
    int z = r3 >> 10;                   // 0..2
    int rem = r3 & 1023;
    int bx = rem & 31, by = rem >> 5;
    const float* W = (z == 0) ? Wq : (z == 1) ? Wk : Wv;
    u16* wt = (z == 0) ? wtq : (z == 1) ? wtk : wtv;
    int k0 = bx * 32, n0 = by * 32;
    int tx = threadIdx.x & 31, ty = threadIdx.x >> 5;
    #pragma unroll
    for(int r = ty; r < 32; r += 8)
      tile[r][tx] = W[(size_t)(k0 + r) * DM + n0 + tx];
    __syncthreads();
    #pragma unroll
    for(int r = ty; r < 32; r += 8)
      wt[(size_t)(n0 + r) * DM + k0 + tx] = f2bf(tile[tx][r]);
  }
}

// ---------------- FUSED QKV projection GEMM (R15): stage A once, feed 3 mats ----------------
// Block = 128m x 128n x ALL THREE matrices, BK=32. Per K-step: stage A (8KB) +
// Bq,Bk,Bv (8KB each); af[] read once from LDS and reused in-register for 3x16
// MFMAs. LDS traffic per mat per K64: 96KB -> 64KB (1.5x on the ~81%-LDS-bound
// kernel); A global fetch /3. Grid 64 mt x 8 panels = 512 blocks = EXACTLY 2
// rounds at 2 resident blocks/CU (64KB LDS) — no dispatch tail (R7 lesson).
// MFMA K-chunk order per mat identical to the unfused kernel (same absmax).
// Swizzle for 64B rows (FIXED vs R13): slot = hi ^ ((row>>1)&3) — bank-verified
// max 2-way aliasing (free, m136); staging source inverse-permuted (rule 21).
// Same 2-phase dbuf schedule: prefetch t+1 issued after the barrier, drained at
// the NEXT barrier. __launch_bounds__(256,2) pins 2 waves/SIMD (acc 192 VGPR).
// V^T store KEY-PERMUTED (attn PV: key 16*hi+4*g+r -> pos 8*g+4*hi+r).
__global__ __launch_bounds__(256, 2) void qkv_fused(
    const u16* __restrict__ xb,
    const u16* __restrict__ wtq, const u16* __restrict__ wtk, const u16* __restrict__ wtv,
    const float* __restrict__ bq, const float* __restrict__ bk, const float* __restrict__ bv,
    u16* __restrict__ qws, u16* __restrict__ kws, u16* __restrict__ vtws){
  __shared__ u16 sa[2][128 * 32];
  __shared__ u16 sq[2][128 * 32];
  __shared__ u16 sk[2][128 * 32];
  __shared__ u16 sv[2][128 * 32];

  const int id = blockIdx.x;              // 0..511
  const int local = id >> 3;              // 0..63 within XCD
  const int mt = (id & 7) * 8 + (local & 7);   // M-tile 0..63 (XCD stripe)
  const int panel = local >> 3;           // n-panel 0..7 (m-inner, L2-hot)
  const int m0 = mt * 128;
  const int n0 = panel * 128;
  const int tid = threadIdx.x;
  const int lane = tid & 63, w = tid >> 6;
  const int ln16 = lane & 15, hi = lane >> 4;
  const int wm = (w >> 1) * 64, wn = (w & 1) * 64;
  const int wb = tid & 192;               // wave-uniform chunk base

  f32x4 aq[4][4] = {}, ak[4][4] = {}, avv[4][4] = {};

  // staging: per buffer 512 chunks of 16B (128 rows x 4 slots), 2 passes x 256 thr.
  // chunk ci: row = ci>>2, slot = ci&3; source k-chunk = slot ^ ((row>>1)&3).
  #define STG(CUR, K0) { \
    _Pragma("unroll") \
    for(int p_ = 0; p_ < 2; p_++){ \
      int base_ = p_ * 256 + wb; \
      int ci_ = base_ + lane; \
      int row_ = ci_ >> 2, chs_ = (ci_ & 3) ^ ((row_ >> 1) & 3); \
      gload16(xb  + (size_t)(m0 + row_) * 1024 + (K0) + chs_ * 8, (char*)sa[CUR] + base_ * 16); \
      gload16(wtq + (size_t)(n0 + row_) * 1024 + (K0) + chs_ * 8, (char*)sq[CUR] + base_ * 16); \
      gload16(wtk + (size_t)(n0 + row_) * 1024 + (K0) + chs_ * 8, (char*)sk[CUR] + base_ * 16); \
      gload16(wtv + (size_t)(n0 + row_) * 1024 + (K0) + chs_ * 8, (char*)sv[CUR] + base_ * 16); \
    } }

  STG(0, 0)                               // stage K-step 0 -> buf 0

  #pragma unroll 1
  for(int kt = 0; kt < 32; kt++){
    const int cur = kt & 1;
    __syncthreads();               // drains vmcnt: buf[cur] ready; buf[cur^1] readers done

    if(kt + 1 < 32){               // prefetch K-step t+1 into buf^1 (drained at next barrier)
      const int k0n = (kt + 1) * 32;
      if(cur == 0){ STG(1, k0n) } else { STG(0, k0n) }
    }

    short8 af[4], bfr[4];
    #pragma unroll
    for(int i = 0; i < 4; i++){
      int ra = wm + i * 16 + ln16;
      af[i] = *(const short8*)((const char*)sa[cur] + ra * 64 + ((hi ^ ((ra >> 1) & 3)) << 4));
    }
    // ---- Q ----
    #pragma unroll
    for(int j = 0; j < 4; j++){
      int rb = wn + j * 16 + ln16;
      bfr[j] = *(const short8*)((const char*)sq[cur] + rb * 64 + ((hi ^ ((rb >> 1) & 3)) << 4));
    }
    __builtin_amdgcn_s_setprio(1);
    #pragma unroll
    for(int i = 0; i < 4; i++)
      #pragma unroll
      for(int j = 0; j < 4; j++)
        aq[i][j] = MFMA(af[i], bfr[j], aq[i][j]);
    __builtin_amdgcn_s_setprio(0);
    // ---- K ----
    #pragma unroll
    for(int j = 0; j < 4; j++){
      int rb = wn + j * 16 + ln16;
      bfr[j] = *(const short8*)((const char*)sk[cur] + rb * 64 + ((hi ^ ((rb >> 1) & 3)) << 4));
    }
    __builtin_amdgcn_s_setprio(1);
    #pragma unroll
    for(int i = 0; i < 4; i++)
      #pragma unroll
      for(int j = 0; j < 4; j++)
        ak[i][j] = MFMA(af[i], bfr[j], ak[i][j]);
    __builtin_amdgcn_s_setprio(0);
    // ---- V ----
    #pragma unroll
    for(int j = 0; j < 4; j++){
      int rb = wn + j * 16 + ln16;
      bfr[j] = *(const short8*)((const char*)sv[cur] + rb * 64 + ((hi ^ ((rb >> 1) & 3)) << 4));
    }
    __builtin_amdgcn_s_setprio(1);
    #pragma unroll
    for(int i = 0; i < 4; i++)
      #pragma unroll
      for(int j = 0; j < 4; j++)
        avv[i][j] = MFMA(af[i], bfr[j], avv[i][j]);
    __builtin_amdgcn_s_setprio(0);
  }
  #undef STG

  // epilogue: Q (scaled), K, V^T (key-permuted for attn's PV b128 reads)
  #pragma unroll
  for(int j = 0; j < 4; j++){
    int n = n0 + wn + j * 16 + ln16;
    float bq_ = bq[n], bk_ = bk[n], bv_ = bv[n];
    int h = n >> 6, d = n & 63;
    #pragma unroll
    for(int i = 0; i < 4; i++){
      int mb = m0 + wm + i * 16 + hi * 4;
      int b = mb >> 11, t = mb & 2047;
      int bh = b * NH + h;
      #pragma unroll
      for(int r = 0; r < 4; r++){
        qws[((size_t)bh * TT + t + r) * DK + d] = f2bf((aq[i][j][r] + bq_) * QSCALE);
        kws[((size_t)bh * TT + t + r) * DK + d] = f2bf(ak[i][j][r] + bk_);
      }
      ushort4 o4;
      o4.x = f2bf(avv[i][j][0] + bv_);
      o4.y = f2bf(avv[i][j][1] + bv_);
      o4.z = f2bf(avv[i][j][2] + bv_);
      o4.w = f2bf(avv[i][j][3] + bv_);
      int tp = (t & ~31) | (((t >> 2) & 3) << 3) | (((t >> 4) & 1) << 2);
      *(ushort4*)(vtws + ((size_t)bh * DK + d) * TT + tp) = o4;
    }
  }
}

// ---------------- flash attention (session-verified best: 8-wave, paired, 16 waves/CU) ----------------
// 8-wave blocks, 128 q-rows per q-tile; per-tile fixed costs amortized over 2x
// q-rows. Grid 512, bijective XCD swizzle (XCD k owns bh in [8k,8k+8), 4MB = its
// L2; FETCH 228MB -> 24.6MB); pairs (x, 15-x) -> every block runs exactly 34
// k-iterations (balanced — R2/R9 lesson: imbalance poisons occupancy). 2
// blocks/CU x 8 waves = 16 waves/CU (R8 lesson: the win condition is >=16
// waves/CU). Lower 4 waves skip their fully-masked final k-tile. VGPR ~56
// (< 64 cliff — R3 lesson). Key-permuted V^T -> conflict-free PV b128 reads
// (R2-verified: SQ_LDS_BANK_CONFLICT 8.65M -> 0). At ~97% of the LDS-service
// model — structural ceiling (32x32 core R8, dual-subtile R9 both regressed).
__global__ __launch_bounds__(512) void attn(
    const u16* __restrict__ qws, const u16* __restrict__ kws, const u16* __restrict__ vtws,
    float* __restrict__ out){
  __shared__ u16 kt[2][64 * 64];    // [buf][key][d]  swizzled
  __shared__ u16 vt[2][64 * 64];    // [buf][d][key-permuted]  swizzled

  const int id = blockIdx.x;
  const int swz = (id & 7) * 64 + (id >> 3);   // bijective (512 % 8 == 0)
  const int qx = swz & 7;                      // pair index 0..7
  const int bh = swz >> 3;

  const int tid = threadIdx.x, lane = tid & 63, w = tid >> 6;   // w 0..7
  const int g = lane >> 4, ln = lane & 15;
  const int b = bh >> 4, h = bh & 15;
  const u16* kbase = kws + (size_t)bh * TT * DK;
  const u16* vbase = vtws + (size_t)bh * DK * TT;
  const int sbase = tid & 448;      // wave-uniform 16B-chunk base (HW adds lane*16)
  const int srow = tid >> 3;        // staging row 0..63
  const int schs = (tid & 7) ^ (srow & 7);     // inverse swizzle on the SOURCE

  #pragma unroll 1
  for(int qi = 0; qi < 2; qi++){
    const int qt = qi ? (15 - qx) : qx;        // 128-row q-tile 0..15
    const int q = qt * 128 + w * 16 + ln;      // this lane's q row

    // Q fragment (B-operand; pre-scaled by QSCALE): k-slots d = g*8+j (+32)
    short8 qf[2];
    {
      const u16* gq = qws + ((size_t)bh * TT + q) * DK + g * 8;
      qf[0] = *(const short8*)gq;
      qf[1] = *(const short8*)(gq + 32);
    }

    f32x4 o[4] = {};                 // O^T frags: o[i][r] = O^T[d=i*16+g*4+r][q]
    float m = -INFINITY, l = 0.f;    // l: per-lane partial sum (reduced in epilogue)

    const int nkt = 2 * qt + 2;            // block-level 64-key tiles
    const int myNkt = nkt - (w < 4 ? 1 : 0);  // lower waves: last tile fully masked

    __syncthreads();                 // prev q-tile readers done; no DMAs outstanding
    // stage k-tile 0 -> buf 0 (async DMA; 512 threads cover 64x64 in one pass)
    gload16(kbase + (size_t)srow * DK + schs * 8, (char*)kt[0] + sbase * 16);
    gload16(vbase + (size_t)srow * TT + schs * 8, (char*)vt[0] + sbase * 16);

    #pragma unroll 1
    for(int kti = 0; kti < nkt; kti++){
      const int cur = kti & 1;
      __syncthreads();               // drains vmcnt: buf[cur] ready; buf[cur^1] readers done

      // async-prefetch next tile straight into buf[cur^1] (drained at next barrier)
      if(kti + 1 < nkt){
        const int k0n = (kti + 1) * 64;
        gload16(kbase + (size_t)(k0n + srow) * DK + schs * 8, (char*)kt[cur ^ 1] + sbase * 16);
        gload16(vbase + (size_t)srow * TT + k0n + schs * 8, (char*)vt[cur ^ 1] + sbase * 16);
      }

      if(kti < myNkt){
        // S^T = K Q : s[i][r] = S[key = k0+i*16+g*4+r][q]
        f32x4 s[4];
        __builtin_amdgcn_s_setprio(1);
        #pragma unroll
        for(int i = 0; i < 4; i++){
          f32x4 c = {};
          #pragma unroll
          for(int ks = 0; ks < 2; ks++){
            int rb = i * 16 + ln;
            int cb = ks * 64 + g * 16;
            short8 kfr = *(const short8*)((const char*)kt[cur] + rb * 128 + (cb ^ ((rb & 7) << 4)));
            c = MFMA(kfr, qf[ks], c);
          }
          s[i] = c;
        }
        __builtin_amdgcn_s_setprio(0);

        if(kti == myNkt - 1){          // causal mask (this wave's diagonal tile)
          const int k0 = kti * 64;
          #pragma unroll
          for(int i = 0; i < 4; i++)
            #pragma unroll
            for(int r = 0; r < 4; r++)
              if(k0 + i * 16 + g * 4 + r > q) s[i][r] = -INFINITY;
        }

        // in-register row max (16 regs) + cross-group permlane swaps (full row = 4 groups)
        float mx0 = fmaxf(fmaxf(s[0][0], s[0][1]), fmaxf(s[0][2], s[0][3]));
        float mx1 = fmaxf(fmaxf(s[1][0], s[1][1]), fmaxf(s[1][2], s[1][3]));
        float mx2 = fmaxf(fmaxf(s[2][0], s[2][1]), fmaxf(s[2][2], s[2][3]));
        float mx3 = fmaxf(fmaxf(s[3][0], s[3][1]), fmaxf(s[3][2], s[3][3]));
        float pmax = fmaxf(fmaxf(mx0, mx1), fmaxf(mx2, mx3));
        pmax = plmax(pmax);

        // defer-max (T13): skip O-rescale when per-tile max growth <= 8 (exp2 domain)
        if(!__all(pmax <= m + 8.f)){
          float mnew = fmaxf(m, pmax);
          float alpha = EXP2(m - mnew);
          l *= alpha;
          #pragma unroll
          for(int i = 0; i < 4; i++)
            #pragma unroll
            for(int r = 0; r < 4; r++) o[i][r] *= alpha;
          m = mnew;
        }

        #pragma unroll
        for(int i = 0; i < 4; i++)
          #pragma unroll
          for(int r = 0; r < 4; r++){
            float p = EXP2(s[i][r] - m);
            s[i][r] = p; l += p;        // per-lane partial only
          }

        // pack P to bf16 B-frags in-register: pb[ks] reg j holds key kappa(g,j)+32ks
        union PU { short8 s8; unsigned w[4]; };
        PU pb[2];
        #pragma unroll
        for(int ks = 0; ks < 2; ks++){
          pb[ks].w[0] = cvtpk(s[2*ks][0],   s[2*ks][1]);
          pb[ks].w[1] = cvtpk(s[2*ks][2],   s[2*ks][3]);
          pb[ks].w[2] = cvtpk(s[2*ks+1][0], s[2*ks+1][1]);
          pb[ks].w[3] = cvtpk(s[2*ks+1][2], s[2*ks+1][3]);
        }

        // O^T += V^T P^T : key-permuted vt makes each A-frag ONE swizzled b128 read
        __builtin_amdgcn_s_setprio(1);
        #pragma unroll
        for(int i = 0; i < 4; i++){
          int dr = i * 16 + ln;
          const char* vrow = (const char*)vt[cur] + dr * 128;
          int sw = (dr & 7) << 4;
          #pragma unroll
          for(int ks = 0; ks < 2; ks++){
            short8 av = *(const short8*)(vrow + ((64 * ks + g * 16) ^ sw));
            o[i] = MFMA(av, pb[ks].s8, o[i]);
          }
        }
        __builtin_amdgcn_s_setprio(0);
      }
    }

    // epilogue: deferred l reduce, then out (B,T,DM) fp32, float4 stores
    l = plsum(l);
    float inv = 1.0f / l;
    float* orow = out + ((size_t)(b * TT + q)) * DM + h * 64 + g * 4;
    #pragma unroll
    for(int i = 0; i < 4; i++){
      float4 v4;
      v4.x = o[i][0] * inv; v4.y = o[i][1] * inv;
      v4.z = o[i][2] * inv; v4.w = o[i][3] * inv;
      *(float4*)(orow + i * 16) = v4;
    }
  }
}

extern "C" void kernel_launch(void* const* d_in, const int* in_sizes, int n_in,
                              void* d_out, int out_size, void* d_ws, size_t ws_size,
                              hipStream_t stream){
  const float* x  = (const float*)d_in[0];
  const float* Wq = (const float*)d_in[1];
  const float* bq = (const float*)d_in[2];
  const float* Wk = (const float*)d_in[3];
  const float* bk = (const float*)d_in[4];
  const float* Wv = (const float*)d_in[5];
  const float* bv = (const float*)d_in[6];
  float* out = (float*)d_out;

  char* ws = (char*)d_ws;
  u16* xb   = (u16*)(ws);                       // 16 MB  x bf16 (M,K)
  u16* wtq  = (u16*)(ws + (16u << 20));         //  2 MB  Wq^T bf16 (N,K)
  u16* wtk  = (u16*)(ws + (18u << 20));
  u16* wtv  = (u16*)(ws + (20u << 20));
  u16* qws  = (u16*)(ws + (22u << 20));         // 16 MB  Q (BH,T,DK) bf16 (pre-scaled)
  u16* kws  = (u16*)(ws + (38u << 20));         // 16 MB  K (BH,T,DK) bf16
  u16* vtws = (u16*)(ws + (54u << 20));         // 16 MB  V^T (BH,DK,T) bf16, key-permuted

  prep<<<dim3(8192 + 3072), dim3(256), 0, stream>>>(x, xb, Wq, Wk, Wv, wtq, wtk, wtv);
  qkv_fused<<<dim3(512), dim3(256), 0, stream>>>(xb, wtq, wtk, wtv, bq, bk, bv, qws, kws, vtws);
  attn<<<dim3(512), dim3(512), 0, stream>>>(qws, kws, vtws, out);
}

// Round 16
// 129.178 us; speedup vs baseline: 1.1646x; 1.0301x over previous
//
#include <hip/hip_runtime.h>
#include <hip/hip_bf16.h>

#define DM 1024
#define NH 16
#define DK 64
#define TT 2048
#define NBATCH 4
#define BT 8192   // NBATCH*TT

typedef __attribute__((ext_vector_type(8))) short short8;
typedef __attribute__((ext_vector_type(4))) float f32x4;
typedef unsigned short u16;

#define MFMA(a,b,c) __builtin_amdgcn_mfma_f32_16x16x32_bf16((a),(b),(c),0,0,0)

// 1/sqrt(64) * log2(e): folded into Q so attn softmax can use exp2 directly
#define QSCALE 0.18033688011112684f

// raw v_exp_f32 (flush-denorm fine for softmax), skips OCML fixup code
#define EXP2(x) __builtin_amdgcn_exp2f(x)

__device__ __forceinline__ u16 f2bf(float f){
  union { float f; unsigned u; } v; v.f = f;
  return (u16)((v.u + 0x7fffu + ((v.u >> 16) & 1u)) >> 16);
}

__device__ __forceinline__ unsigned cvtpk(float lo, float hi){
  unsigned r;
  asm("v_cvt_pk_bf16_f32 %0, %1, %2" : "=v"(r) : "v"(lo), "v"(hi));
  return r;
}

// async global->LDS DMA, 16B/lane. LDS dest must be wave-uniform base (+lane*16).
__device__ __forceinline__ void gload16(const void* g, void* l){
  __builtin_amdgcn_global_load_lds((__attribute__((address_space(1))) void*)(g),
                                   (__attribute__((address_space(3))) void*)(l), 16, 0, 0);
}

// cross-lane reduce over the 4 16-lane groups (lane ^16, ^32): pure-VALU permlanes
__device__ __forceinline__ float plmax(float x){
#if __has_builtin(__builtin_amdgcn_permlane16_swap) && __has_builtin(__builtin_amdgcn_permlane32_swap)
  auto r = __builtin_amdgcn_permlane16_swap(__float_as_uint(x), __float_as_uint(x), false, false);
  x = fmaxf(__uint_as_float(r[0]), __uint_as_float(r[1]));
  auto r2 = __builtin_amdgcn_permlane32_swap(__float_as_uint(x), __float_as_uint(x), false, false);
  x = fmaxf(__uint_as_float(r2[0]), __uint_as_float(r2[1]));
#else
  x = fmaxf(x, __shfl_xor(x, 16, 64));
  x = fmaxf(x, __shfl_xor(x, 32, 64));
#endif
  return x;
}

__device__ __forceinline__ float plsum(float x){
#if __has_builtin(__builtin_amdgcn_permlane16_swap) && __has_builtin(__builtin_amdgcn_permlane32_swap)
  auto r = __builtin_amdgcn_permlane16_swap(__float_as_uint(x), __float_as_uint(x), false, false);
  x = __uint_as_float(r[0]) + __uint_as_float(r[1]);
  auto r2 = __builtin_amdgcn_permlane32_swap(__float_as_uint(x), __float_as_uint(x), false, false);
  x = __uint_as_float(r2[0]) + __uint_as_float(r2[1]);
#else
  x = x + __shfl_xor(x, 16, 64);
  x = x + __shfl_xor(x, 32, 64);
#endif
  return x;
}

// ---------------- prep: x fp32->bf16  +  W (K,N) fp32 -> wt (N,K) bf16 ----------------
// merged single launch (block-uniform branch): blocks [0,8192) convert x,
// blocks [8192, 8192+3072) transpose+convert the three weight matrices.
__global__ __launch_bounds__(256) void prep(
    const float* __restrict__ x, u16* __restrict__ xb,
    const float* __restrict__ Wq, const float* __restrict__ Wk, const float* __restrict__ Wv,
    u16* __restrict__ wtq, u16* __restrict__ wtk, u16* __restrict__ wtv){
  __shared__ float tile[32][33];
  const int id = blockIdx.x;
  if(id < 8192){
    int i = (id * 256 + threadIdx.x) * 4;
    float4 v = *(const float4*)(x + i);
    ushort4 o; o.x = f2bf(v.x); o.y = f2bf(v.y); o.z = f2bf(v.z); o.w = f2bf(v.w);
    *(ushort4*)(xb + i) = o;
  } else {
    int r3 = id - 8192;                 // 0..3071
    int z = r3 >> 10;                   // 0..2
    int rem = r3 & 1023;
    int bx = rem & 31, by = rem >> 5;
    const float* W = (z == 0) ? Wq : (z == 1) ? Wk : Wv;
    u16* wt = (z == 0) ? wtq : (z == 1) ? wtk : wtv;
    int k0 = bx * 32, n0 = by * 32;
    int tx = threadIdx.x & 31, ty = threadIdx.x >> 5;
    #pragma unroll
    for(int r = ty; r < 32; r += 8)
      tile[r][tx] = W[(size_t)(k0 + r) * DM + n0 + tx];
    __syncthreads();
    #pragma unroll
    for(int r = ty; r < 32; r += 8)
      wt[(size_t)(n0 + r) * DM + k0 + tx] = f2bf(tile[tx][r]);
  }
}

// ---------------- FUSED QKV projection GEMM (R15-verified, ~58us): stage A once ----------------
// Block = 128m x 128n x ALL THREE matrices, BK=32. Per K-step: stage A (8KB) +
// Bq,Bk,Bv (8KB each); af[] read once from LDS and reused in-register for 3x16
// MFMAs. LDS traffic per mat per K64: 96KB -> 64KB; A global fetch /3. Grid 64
// mt x 8 panels = 512 blocks = EXACTLY 2 rounds at 2 resident blocks/CU (64KB
// LDS) — no dispatch tail. Swizzle for 64B rows: slot = hi ^ ((row>>1)&3)
// (bank-verified max 2-way = free); staging source inverse-permuted (rule 21).
// 2-phase dbuf schedule: prefetch t+1 issued after the barrier, drained at the
// NEXT barrier. V^T store KEY-PERMUTED (attn PV: key 16*hi+4*g+r -> pos 8*g+4*hi+r).
__global__ __launch_bounds__(256, 2) void qkv_fused(
    const u16* __restrict__ xb,
    const u16* __restrict__ wtq, const u16* __restrict__ wtk, const u16* __restrict__ wtv,
    const float* __restrict__ bq, const float* __restrict__ bk, const float* __restrict__ bv,
    u16* __restrict__ qws, u16* __restrict__ kws, u16* __restrict__ vtws){
  __shared__ u16 sa[2][128 * 32];
  __shared__ u16 sq[2][128 * 32];
  __shared__ u16 sk[2][128 * 32];
  __shared__ u16 sv[2][128 * 32];

  const int id = blockIdx.x;              // 0..511
  const int local = id >> 3;              // 0..63 within XCD
  const int mt = (id & 7) * 8 + (local & 7);   // M-tile 0..63 (XCD stripe)
  const int panel = local >> 3;           // n-panel 0..7 (m-inner, L2-hot)
  const int m0 = mt * 128;
  const int n0 = panel * 128;
  const int tid = threadIdx.x;
  const int lane = tid & 63, w = tid >> 6;
  const int ln16 = lane & 15, hi = lane >> 4;
  const int wm = (w >> 1) * 64, wn = (w & 1) * 64;
  const int wb = tid & 192;               // wave-uniform chunk base

  f32x4 aq[4][4] = {}, ak[4][4] = {}, avv[4][4] = {};

  // staging: per buffer 512 chunks of 16B (128 rows x 4 slots), 2 passes x 256 thr.
  // chunk ci: row = ci>>2, slot = ci&3; source k-chunk = slot ^ ((row>>1)&3).
  #define STG(CUR, K0) { \
    _Pragma("unroll") \
    for(int p_ = 0; p_ < 2; p_++){ \
      int base_ = p_ * 256 + wb; \
      int ci_ = base_ + lane; \
      int row_ = ci_ >> 2, chs_ = (ci_ & 3) ^ ((row_ >> 1) & 3); \
      gload16(xb  + (size_t)(m0 + row_) * 1024 + (K0) + chs_ * 8, (char*)sa[CUR] + base_ * 16); \
      gload16(wtq + (size_t)(n0 + row_) * 1024 + (K0) + chs_ * 8, (char*)sq[CUR] + base_ * 16); \
      gload16(wtk + (size_t)(n0 + row_) * 1024 + (K0) + chs_ * 8, (char*)sk[CUR] + base_ * 16); \
      gload16(wtv + (size_t)(n0 + row_) * 1024 + (K0) + chs_ * 8, (char*)sv[CUR] + base_ * 16); \
    } }

  STG(0, 0)                               // stage K-step 0 -> buf 0

  #pragma unroll 1
  for(int kt = 0; kt < 32; kt++){
    const int cur = kt & 1;
    __syncthreads();               // drains vmcnt: buf[cur] ready; buf[cur^1] readers done

    if(kt + 1 < 32){               // prefetch K-step t+1 into buf^1 (drained at next barrier)
      const int k0n = (kt + 1) * 32;
      if(cur == 0){ STG(1, k0n) } else { STG(0, k0n) }
    }

    short8 af[4], bfr[4];
    #pragma unroll
    for(int i = 0; i < 4; i++){
      int ra = wm + i * 16 + ln16;
      af[i] = *(const short8*)((const char*)sa[cur] + ra * 64 + ((hi ^ ((ra >> 1) & 3)) << 4));
    }
    // ---- Q ----
    #pragma unroll
    for(int j = 0; j < 4; j++){
      int rb = wn + j * 16 + ln16;
      bfr[j] = *(const short8*)((const char*)sq[cur] + rb * 64 + ((hi ^ ((rb >> 1) & 3)) << 4));
    }
    __builtin_amdgcn_s_setprio(1);
    #pragma unroll
    for(int i = 0; i < 4; i++)
      #pragma unroll
      for(int j = 0; j < 4; j++)
        aq[i][j] = MFMA(af[i], bfr[j], aq[i][j]);
    __builtin_amdgcn_s_setprio(0);
    // ---- K ----
    #pragma unroll
    for(int j = 0; j < 4; j++){
      int rb = wn + j * 16 + ln16;
      bfr[j] = *(const short8*)((const char*)sk[cur] + rb * 64 + ((hi ^ ((rb >> 1) & 3)) << 4));
    }
    __builtin_amdgcn_s_setprio(1);
    #pragma unroll
    for(int i = 0; i < 4; i++)
      #pragma unroll
      for(int j = 0; j < 4; j++)
        ak[i][j] = MFMA(af[i], bfr[j], ak[i][j]);
    __builtin_amdgcn_s_setprio(0);
    // ---- V ----
    #pragma unroll
    for(int j = 0; j < 4; j++){
      int rb = wn + j * 16 + ln16;
      bfr[j] = *(const short8*)((const char*)sv[cur] + rb * 64 + ((hi ^ ((rb >> 1) & 3)) << 4));
    }
    __builtin_amdgcn_s_setprio(1);
    #pragma unroll
    for(int i = 0; i < 4; i++)
      #pragma unroll
      for(int j = 0; j < 4; j++)
        avv[i][j] = MFMA(af[i], bfr[j], avv[i][j]);
    __builtin_amdgcn_s_setprio(0);
  }
  #undef STG

  // epilogue: Q (scaled), K, V^T (key-permuted for attn's PV b128 reads)
  #pragma unroll
  for(int j = 0; j < 4; j++){
    int n = n0 + wn + j * 16 + ln16;
    float bq_ = bq[n], bk_ = bk[n], bv_ = bv[n];
    int h = n >> 6, d = n & 63;
    #pragma unroll
    for(int i = 0; i < 4; i++){
      int mb = m0 + wm + i * 16 + hi * 4;
      int b = mb >> 11, t = mb & 2047;
      int bh = b * NH + h;
      #pragma unroll
      for(int r = 0; r < 4; r++){
        qws[((size_t)bh * TT + t + r) * DK + d] = f2bf((aq[i][j][r] + bq_) * QSCALE);
        kws[((size_t)bh * TT + t + r) * DK + d] = f2bf(ak[i][j][r] + bk_);
      }
      ushort4 o4;
      o4.x = f2bf(avv[i][j][0] + bv_);
      o4.y = f2bf(avv[i][j][1] + bv_);
      o4.z = f2bf(avv[i][j][2] + bv_);
      o4.w = f2bf(avv[i][j][3] + bv_);
      int tp = (t & ~31) | (((t >> 2) & 3) << 3) | (((t >> 4) & 1) << 2);
      *(ushort4*)(vtws + ((size_t)bh * DK + d) * TT + tp) = o4;
    }
  }
}

// ---------------- flash attention: 8-wave + R2 fused-bias softmax (R16) ----------------
// Session-verified 8-wave structure (grid 512, XCD-bijective, paired (x,15-x)
// -> exactly 34 iters/block, 16 waves/CU, conflict-free PV) + the R2 VALU-saving
// inner loop, now affordable: base VGPR was 40, the 64-cliff headroom absorbs
// the graft (R3's failure was the 4-wave base at 60 -> 72 crossing the cliff).
// (a) MFMA C-init = -m: fast path p = exp2(s), NO per-score subtract;
// (b) max3-fusable fmax chains; (c) vector f32x4 lv; (d) rescale path (~1/block)
// carries the subtract. Numerics identical to the R2-validated kernel.
__global__ __launch_bounds__(512) void attn(
    const u16* __restrict__ qws, const u16* __restrict__ kws, const u16* __restrict__ vtws,
    float* __restrict__ out){
  __shared__ u16 kt[2][64 * 64];    // [buf][key][d]  swizzled
  __shared__ u16 vt[2][64 * 64];    // [buf][d][key-permuted]  swizzled

  const int id = blockIdx.x;
  const int swz = (id & 7) * 64 + (id >> 3);   // bijective (512 % 8 == 0)
  const int qx = swz & 7;                      // pair index 0..7
  const int bh = swz >> 3;

  const int tid = threadIdx.x, lane = tid & 63, w = tid >> 6;   // w 0..7
  const int g = lane >> 4, ln = lane & 15;
  const int b = bh >> 4, h = bh & 15;
  const u16* kbase = kws + (size_t)bh * TT * DK;
  const u16* vbase = vtws + (size_t)bh * DK * TT;
  const int sbase = tid & 448;      // wave-uniform 16B-chunk base (HW adds lane*16)
  const int srow = tid >> 3;        // staging row 0..63
  const int schs = (tid & 7) ^ (srow & 7);     // inverse swizzle on the SOURCE

  #pragma unroll 1
  for(int qi = 0; qi < 2; qi++){
    const int qt = qi ? (15 - qx) : qx;        // 128-row q-tile 0..15
    const int q = qt * 128 + w * 16 + ln;      // this lane's q row

    // Q fragment (B-operand; pre-scaled by QSCALE): k-slots d = g*8+j (+32)
    short8 qf[2];
    {
      const u16* gq = qws + ((size_t)bh * TT + q) * DK + g * 8;
      qf[0] = *(const short8*)gq;
      qf[1] = *(const short8*)(gq + 32);
    }

    f32x4 o[4] = {};                 // O^T frags: o[i][r] = O^T[d=i*16+g*4+r][q]
    f32x4 lv = {};                   // per-lane vector partial sum (epilogue-reduced)
    float m = -INFINITY, mneg = 0.f; // running max; -m is the MFMA C-in bias

    const int nkt = 2 * qt + 2;            // block-level 64-key tiles
    const int myNkt = nkt - (w < 4 ? 1 : 0);  // lower waves: last tile fully masked

    __syncthreads();                 // prev q-tile readers done; no DMAs outstanding
    // stage k-tile 0 -> buf 0 (async DMA; 512 threads cover 64x64 in one pass)
    gload16(kbase + (size_t)srow * DK + schs * 8, (char*)kt[0] + sbase * 16);
    gload16(vbase + (size_t)srow * TT + schs * 8, (char*)vt[0] + sbase * 16);

    #pragma unroll 1
    for(int kti = 0; kti < nkt; kti++){
      const int cur = kti & 1;
      __syncthreads();               // drains vmcnt: buf[cur] ready; buf[cur^1] readers done

      // async-prefetch next tile straight into buf[cur^1] (drained at next barrier)
      if(kti + 1 < nkt){
        const int k0n = (kti + 1) * 64;
        gload16(kbase + (size_t)(k0n + srow) * DK + schs * 8, (char*)kt[cur ^ 1] + sbase * 16);
        gload16(vbase + (size_t)srow * TT + k0n + schs * 8, (char*)vt[cur ^ 1] + sbase * 16);
      }

      if(kti < myNkt){
        // S^T = K Q - m : s[i][r] = S[key = k0+i*16+g*4+r][q] - m  (bias via C-in)
        f32x4 s[4];
        __builtin_amdgcn_s_setprio(1);
        #pragma unroll
        for(int i = 0; i < 4; i++){
          f32x4 c = {mneg, mneg, mneg, mneg};
          #pragma unroll
          for(int ks = 0; ks < 2; ks++){
            int rb = i * 16 + ln;
            int cb = ks * 64 + g * 16;
            short8 kfr = *(const short8*)((const char*)kt[cur] + rb * 128 + (cb ^ ((rb & 7) << 4)));
            c = MFMA(kfr, qf[ks], c);
          }
          s[i] = c;
        }
        __builtin_amdgcn_s_setprio(0);

        if(kti == myNkt - 1){          // causal mask (this wave's diagonal tile)
          const int k0 = kti * 64;
          #pragma unroll
          for(int i = 0; i < 4; i++)
            #pragma unroll
            for(int r = 0; r < 4; r++)
              if(k0 + i * 16 + g * 4 + r > q) s[i][r] = -INFINITY;
        }

        // biased row max: 4-long chains fuse to v_max3; cross-group permlanes
        float mx0 = fmaxf(fmaxf(fmaxf(s[0][0], s[0][1]), s[0][2]), s[0][3]);
        float mx1 = fmaxf(fmaxf(fmaxf(s[1][0], s[1][1]), s[1][2]), s[1][3]);
        float mx2 = fmaxf(fmaxf(fmaxf(s[2][0], s[2][1]), s[2][2]), s[2][3]);
        float mx3 = fmaxf(fmaxf(fmaxf(s[3][0], s[3][1]), s[3][2]), s[3][3]);
        float pmax = fmaxf(fmaxf(fmaxf(mx0, mx1), mx2), mx3);
        pmax = plmax(pmax);            // true tile max = pmax - mneg (per q-row)

        if(__all(pmax - mneg <= m + 8.f)){
          // fast path (defer-max): NO subtract — s is already score - m
          #pragma unroll
          for(int i = 0; i < 4; i++){
            f32x4 p;
            p[0] = EXP2(s[i][0]); p[1] = EXP2(s[i][1]);
            p[2] = EXP2(s[i][2]); p[3] = EXP2(s[i][3]);
            s[i] = p; lv += p;
          }
        } else {
          // rescale path (first tile + rare growth)
          float mnew = fmaxf(m, pmax - mneg);
          float alpha = EXP2(m - mnew);          // exp2(-inf)=0 on first tile
          lv *= alpha;
          #pragma unroll
          for(int i = 0; i < 4; i++) o[i] *= alpha;
          float d = mnew + mneg;                 // s - d = score - mnew
          m = mnew; mneg = -mnew;
          #pragma unroll
          for(int i = 0; i < 4; i++){
            f32x4 p;
            p[0] = EXP2(s[i][0] - d); p[1] = EXP2(s[i][1] - d);
            p[2] = EXP2(s[i][2] - d); p[3] = EXP2(s[i][3] - d);
            s[i] = p; lv += p;
          }
        }

        // pack P to bf16 B-frags in-register: pb[ks] reg j holds key kappa(g,j)+32ks
        union PU { short8 s8; unsigned w[4]; };
        PU pb[2];
        #pragma unroll
        for(int ks = 0; ks < 2; ks++){
          pb[ks].w[0] = cvtpk(s[2*ks][0],   s[2*ks][1]);
          pb[ks].w[1] = cvtpk(s[2*ks][2],   s[2*ks][3]);
          pb[ks].w[2] = cvtpk(s[2*ks+1][0], s[2*ks+1][1]);
          pb[ks].w[3] = cvtpk(s[2*ks+1][2], s[2*ks+1][3]);
        }

        // O^T += V^T P^T : key-permuted vt makes each A-frag ONE swizzled b128 read
        __builtin_amdgcn_s_setprio(1);
        #pragma unroll
        for(int i = 0; i < 4; i++){
          int dr = i * 16 + ln;
          const char* vrow = (const char*)vt[cur] + dr * 128;
          int sw = (dr & 7) << 4;
          #pragma unroll
          for(int ks = 0; ks < 2; ks++){
            short8 av = *(const short8*)(vrow + ((64 * ks + g * 16) ^ sw));
            o[i] = MFMA(av, pb[ks].s8, o[i]);
          }
        }
        __builtin_amdgcn_s_setprio(0);
      }
    }

    // epilogue: deferred l reduce, then out (B,T,DM) fp32, float4 stores
    float l = (lv[0] + lv[1]) + (lv[2] + lv[3]);
    l = plsum(l);
    float inv = 1.0f / l;
    float* orow = out + ((size_t)(b * TT + q)) * DM + h * 64 + g * 4;
    #pragma unroll
    for(int i = 0; i < 4; i++){
      float4 v4;
      v4.x = o[i][0] * inv; v4.y = o[i][1] * inv;
      v4.z = o[i][2] * inv; v4.w = o[i][3] * inv;
      *(float4*)(orow + i * 16) = v4;
    }
  }
}

extern "C" void kernel_launch(void* const* d_in, const int* in_sizes, int n_in,
                              void* d_out, int out_size, void* d_ws, size_t ws_size,
                              hipStream_t stream){
  const float* x  = (const float*)d_in[0];
  const float* Wq = (const float*)d_in[1];
  const float* bq = (const float*)d_in[2];
  const float* Wk = (const float*)d_in[3];
  const float* bk = (const float*)d_in[4];
  const float* Wv = (const float*)d_in[5];
  const float* bv = (const float*)d_in[6];
  float* out = (float*)d_out;

  char* ws = (char*)d_ws;
  u16* xb   = (u16*)(ws);                       // 16 MB  x bf16 (M,K)
  u16* wtq  = (u16*)(ws + (16u << 20));         //  2 MB  Wq^T bf16 (N,K)
  u16* wtk  = (u16*)(ws + (18u << 20));
  u16* wtv  = (u16*)(ws + (20u << 20));
  u16* qws  = (u16*)(ws + (22u << 20));         // 16 MB  Q (BH,T,DK) bf16 (pre-scaled)
  u16* kws  = (u16*)(ws + (38u << 20));         // 16 MB  K (BH,T,DK) bf16
  u16* vtws = (u16*)(ws + (54u << 20));         // 16 MB  V^T (BH,DK,T) bf16, key-permuted

  prep<<<dim3(8192 + 3072), dim3(256), 0, stream>>>(x, xb, Wq, Wk, Wv, wtq, wtk, wtv);
  qkv_fused<<<dim3(512), dim3(256), 0, stream>>>(xb, wtq, wtk, wtv, bq, bk, bv, qws, kws, vtws);
  attn<<<dim3(512), dim3(512), 0, stream>>>(qws, kws, vtws, out);
}